// Round 9
// baseline (137.084 us; speedup 1.0000x reference)
//
#include <hip/hip_runtime.h>

// ============================================================================
// DIAGNOSTIC ROUND: kernels repeated (prep x16, pointsift x4) with identical,
// idempotent work per rep so both dispatches exceed the 39us profile cutoff
// and return full rocprof counters. Output is bit-identical to the 1x kernel.
// Next round reverts to 1x with the counter-guided fix.
// ============================================================================

#define NPTS 2048
#define CCH  256
#define CAP  320          // per-wave compaction capacity
#define CAPU (CAP - 64)   // final cnt <= CAPU guarantees complete list
#define PREP_REPS 16
#define SIFT_REPS 4

// ---- DPP cross-lane helpers (VALU pipe, no LDS) ----
template <int CTRL>
__device__ __forceinline__ float dppf(float v) {
    return __int_as_float(__builtin_amdgcn_update_dpp(
        0, __float_as_int(v), CTRL, 0xF, 0xF, true));
}
__device__ __forceinline__ float row16_max(float v) {
    v = fmaxf(v, dppf<0xB1>(v));
    v = fmaxf(v, dppf<0x4E>(v));
    v = fmaxf(v, dppf<0x141>(v));
    v = fmaxf(v, dppf<0x140>(v));
    return v;
}
__device__ __forceinline__ float row16_min(float v) {
    v = fminf(v, dppf<0xB1>(v));
    v = fminf(v, dppf<0x4E>(v));
    v = fminf(v, dppf<0x141>(v));
    v = fminf(v, dppf<0x140>(v));
    return v;
}
__device__ __forceinline__ float row16_sum(float v) {
    v += dppf<0xB1>(v);
    v += dppf<0x4E>(v);
    v += dppf<0x141>(v);
    v += dppf<0x140>(v);
    return v;
}
__device__ __forceinline__ float wave_sum(float v) {
    v = row16_sum(v);
    v += __shfl_xor(v, 16, 64);
    v += __shfl_xor(v, 32, 64);
    return v;
}

// ws layout (floats): [0..767] W_eff (256x3 row-major), [768..1023] b_eff

// ---------------------------------------------------------------------------
// Merged prep (R5 structure, 8-acc ILP), repeated PREP_REPS times.
// ---------------------------------------------------------------------------
__global__ __launch_bounds__(256) void prep_kernel(
    const float* __restrict__ w1, const float* __restrict__ b1,
    const float* __restrict__ w2, const float* __restrict__ b2,
    const float* __restrict__ w3, const float* __restrict__ b3,
    float* __restrict__ ws)
{
    __shared__ float  w3row[CCH];
    __shared__ float4 wpart[4];
    int o = blockIdx.x, c = threadIdx.x;

    for (int rep = 0; rep < PREP_REPS; ++rep) {
        __syncthreads();                 // protect w3row/wpart across reps
        float w3c = w3[o * CCH + c];     // coalesced
        w3row[c] = w3c;
        __syncthreads();

        float a0 = 0.f, a1 = 0.f, a2 = 0.f, a3 = 0.f;
        float a4 = 0.f, a5 = 0.f, a6 = 0.f, a7 = 0.f;
        const float* w2c = w2 + c;
        for (int k = 0; k < CCH; k += 8) {
            a0 = fmaf(w3row[k + 0], w2c[(k + 0) * CCH], a0);
            a1 = fmaf(w3row[k + 1], w2c[(k + 1) * CCH], a1);
            a2 = fmaf(w3row[k + 2], w2c[(k + 2) * CCH], a2);
            a3 = fmaf(w3row[k + 3], w2c[(k + 3) * CCH], a3);
            a4 = fmaf(w3row[k + 4], w2c[(k + 4) * CCH], a4);
            a5 = fmaf(w3row[k + 5], w2c[(k + 5) * CCH], a5);
            a6 = fmaf(w3row[k + 6], w2c[(k + 6) * CCH], a6);
            a7 = fmaf(w3row[k + 7], w2c[(k + 7) * CCH], a7);
        }
        float acc = ((a0 + a1) + (a2 + a3)) + ((a4 + a5) + (a6 + a7));

        float4 v = make_float4(acc * w1[c * 3 + 0],
                               acc * w1[c * 3 + 1],
                               acc * w1[c * 3 + 2],
                               fmaf(acc, b1[c], w3c * b2[c]));
        v.x = wave_sum(v.x);
        v.y = wave_sum(v.y);
        v.z = wave_sum(v.z);
        v.w = wave_sum(v.w);
        if ((c & 63) == 0) wpart[c >> 6] = v;
        __syncthreads();
        if (c == 0) {
            float4 p0 = wpart[0], p1 = wpart[1], p2 = wpart[2], p3 = wpart[3];
            ws[o * 3 + 0] = (p0.x + p1.x) + (p2.x + p3.x);
            ws[o * 3 + 1] = (p0.y + p1.y) + (p2.y + p3.y);
            ws[o * 3 + 2] = (p0.z + p1.z) + (p2.z + p3.z);
            ws[3 * CCH + o] = (p0.w + p1.w) + (p2.w + p3.w) + b3[o];
        }
    }
}

// ---------------------------------------------------------------------------
// pointsift (exact R5 structure: 1024 thr, LDS stage, ballot compaction),
// repeated SIFT_REPS times idempotently.
// ---------------------------------------------------------------------------
__global__ __launch_bounds__(1024) void pointsift_kernel(
    const float* __restrict__ x,   // [Bp, NPTS, 3]
    const float* __restrict__ ws,  // W_eff[256*3] then b_eff[256]
    float* __restrict__ out)       // [Bp, NPTS, 21]
{
    __shared__ float4 sx4[NPTS];                   // 32 KB
    __shared__ unsigned short slist[16][CAP];      // 10 KB

    int batch = blockIdx.x >> 7;                   // 128 blocks per batch
    int n0    = (blockIdx.x & 127) * 16;
    const float* xb = x + (size_t)batch * NPTS * 3;

    int wave = threadIdx.x >> 6;
    int lane = threadIdx.x & 63;
    int n = n0 + wave;

    for (int rep = 0; rep < SIFT_REPS; ++rep) {
        for (int i = threadIdx.x; i < NPTS; i += 1024) {
            float3 p = *(const float3*)(xb + 3 * i);
            sx4[i] = make_float4(p.x, p.y, p.z, 0.f);
        }

        float3 cpt = *(const float3*)(xb + 3 * n);
        float cx = cpt.x, cy = cpt.y, cz = cpt.z;

        __syncthreads();                           // sx4 ready

        unsigned short* slw = slist[wave];

        // ---- pass 1: validity + wave compaction ----
        unsigned cnt = 0;
#pragma unroll 4
        for (int m = lane; m < NPTS; m += 64) {
            float4 p = sx4[m];
            float dx = p.x - cx, dy = p.y - cy, dz = p.z - cz;
            float d2 = __fadd_rn(__fadd_rn(__fmul_rn(dx, dx), __fmul_rn(dy, dy)),
                                 __fmul_rn(dz, dz));
            bool valid = (d2 > 1e-10f) && (d2 < 0.0625f);
            unsigned long long mask = __ballot(valid);
            if (valid && cnt <= CAPU) {
                unsigned below = __builtin_amdgcn_mbcnt_hi(
                    (unsigned)(mask >> 32),
                    __builtin_amdgcn_mbcnt_lo((unsigned)mask, 0u));
                slw[cnt + below] = (unsigned short)m;
            }
            cnt += (unsigned)__popcll(mask);
        }

        // ---- pass 2: per-octant best ----
        float bd[8];
        int   bi[8];
#pragma unroll
        for (int i = 0; i < 8; ++i) { bd[i] = __builtin_inff(); bi[i] = n; }

        if (cnt <= CAPU) {
            int cn = (int)cnt;
            for (int t = lane; t < cn; t += 64) {
                int m = slw[t];
                float4 p = sx4[m];
                float dx = p.x - cx, dy = p.y - cy, dz = p.z - cz;
                float d2 = __fadd_rn(__fadd_rn(__fmul_rn(dx, dx), __fmul_rn(dy, dy)),
                                     __fmul_rn(dz, dz));
                int oct = 4 * (int)(dx + 1.0f) + 2 * (int)(dy + 1.0f) + (int)(dz + 1.0f);
#pragma unroll
                for (int i = 0; i < 8; ++i) {
                    bool upd = (oct == i) && (d2 < bd[i]);
                    bd[i] = upd ? d2 : bd[i];
                    bi[i] = upd ? m : bi[i];
                }
            }
        } else {
            for (int m = lane; m < NPTS; m += 64) {
                float4 p = sx4[m];
                float dx = p.x - cx, dy = p.y - cy, dz = p.z - cz;
                float d2 = __fadd_rn(__fadd_rn(__fmul_rn(dx, dx), __fmul_rn(dy, dy)),
                                     __fmul_rn(dz, dz));
                bool valid = (d2 > 1e-10f) && (d2 < 0.0625f);
                int oct = 4 * (int)(dx + 1.0f) + 2 * (int)(dy + 1.0f) + (int)(dz + 1.0f);
#pragma unroll
                for (int i = 0; i < 8; ++i) {
                    bool upd = valid && (oct == i) && (d2 < bd[i]);
                    bd[i] = upd ? d2 : bd[i];
                    bi[i] = upd ? m : bi[i];
                }
            }
        }

        // ---- cross-lane argmin ----
        int nidx[8];
#pragma unroll
        for (int i = 0; i < 8; ++i) {
            float mv = row16_min(bd[i]);
            mv = fminf(mv, __shfl_xor(mv, 16, 64));
            mv = fminf(mv, __shfl_xor(mv, 32, 64));
            unsigned long long mk = __ballot(bd[i] == mv);
            if (__popcll(mk) == 1) {
                nidx[i] = __builtin_amdgcn_readlane(bi[i], (int)__builtin_ctzll(mk));
            } else {
                int mm = (bd[i] == mv) ? bi[i] : 0x7FFFFFFF;
#pragma unroll
                for (int s = 32; s > 0; s >>= 1) {
                    int o = __shfl_xor(mm, s, 64);
                    mm = o < mm ? o : mm;
                }
                nidx[i] = mm;
            }
        }

        // ---- fused affine + SPP ----
        const float4* wsv = (const float4*)ws;
        float4 wa = wsv[lane * 3 + 0];
        float4 wb = wsv[lane * 3 + 1];
        float4 wc = wsv[lane * 3 + 2];
        float4 be = ((const float4*)(ws + 3 * CCH))[lane];
        float w[4][3] = {{wa.x, wa.y, wa.z}, {wa.w, wb.x, wb.y},
                         {wb.z, wb.w, wc.x}, {wc.y, wc.z, wc.w}};
        float bev[4] = {be.x, be.y, be.z, be.w};

        float m16[4];
#pragma unroll
        for (int i = 0; i < 4; ++i) m16[i] = -__builtin_inff();
#pragma unroll
        for (int k = 0; k < 8; ++k) {
            float4 p = sx4[nidx[k]];
            float gx = p.x - cx, gy = p.y - cy, gz = p.z - cz;
#pragma unroll
            for (int q = 0; q < 4; ++q) {
                float h = fmaf(gx, w[q][0], fmaf(gy, w[q][1], fmaf(gz, w[q][2], bev[q])));
                m16[k >> 1] = fmaxf(m16[k >> 1], h);
            }
        }

        float t[4], u[4];
#pragma unroll
        for (int i = 0; i < 4; ++i) {
            m16[i] = row16_max(m16[i]);
            t[i] = fmaxf(m16[i], __shfl_xor(m16[i], 16, 64));
            u[i] = fmaxf(t[i], __shfl_xor(t[i], 32, 64));
        }

        float* op = out + ((size_t)batch * NPTS + n) * 21;
        if ((lane & 15) == 0) {
            int j = lane >> 4;
#pragma unroll
            for (int i = 0; i < 4; ++i)
                op[i * 4 + j] = m16[i];
        }
        if (lane == 0 || lane == 32) {
            int j2 = lane >> 5;
            op[16 + 0 * 2 + j2] = fmaxf(t[0], t[1]);
            op[16 + 1 * 2 + j2] = fmaxf(t[2], t[3]);
        }
        if (lane == 0) {
            op[20] = fmaxf(fmaxf(u[0], u[1]), fmaxf(u[2], u[3]));
        }

        __syncthreads();                           // before next rep re-stages
    }
}

extern "C" void kernel_launch(void* const* d_in, const int* in_sizes, int n_in,
                              void* d_out, int out_size, void* d_ws, size_t ws_size,
                              hipStream_t stream) {
    const float* x  = (const float*)d_in[0];
    const float* w1 = (const float*)d_in[1];
    const float* b1 = (const float*)d_in[2];
    const float* w2 = (const float*)d_in[3];
    const float* b2 = (const float*)d_in[4];
    const float* w3 = (const float*)d_in[5];
    const float* b3 = (const float*)d_in[6];
    float* out = (float*)d_out;
    float* ws  = (float*)d_ws;

    prep_kernel<<<CCH, CCH, 0, stream>>>(w1, b1, w2, b2, w3, b3, ws);

    int Bp = in_sizes[0] / (NPTS * 3);             // B*T = 4
    pointsift_kernel<<<Bp * (NPTS / 16), 1024, 0, stream>>>(x, ws, out);
}

// Round 10
// 26.327 us; speedup vs baseline: 5.2070x; 5.2070x over previous
//
#include <hip/hip_runtime.h>

#define NPTS 2048
#define CCH  256
#define CAP  320          // per-wave compaction capacity
#define CAPU (CAP - 64)   // final cnt <= CAPU guarantees complete list

// ---- DPP cross-lane helpers (VALU pipe, no LDS) ----
template <int CTRL>
__device__ __forceinline__ float dppf(float v) {
    return __int_as_float(__builtin_amdgcn_update_dpp(
        0, __float_as_int(v), CTRL, 0xF, 0xF, true));
}
__device__ __forceinline__ float row16_max(float v) {
    v = fmaxf(v, dppf<0xB1>(v));
    v = fmaxf(v, dppf<0x4E>(v));
    v = fmaxf(v, dppf<0x141>(v));
    v = fmaxf(v, dppf<0x140>(v));
    return v;
}
__device__ __forceinline__ float row16_min(float v) {
    v = fminf(v, dppf<0xB1>(v));
    v = fminf(v, dppf<0x4E>(v));
    v = fminf(v, dppf<0x141>(v));
    v = fminf(v, dppf<0x140>(v));
    return v;
}
__device__ __forceinline__ float row16_sum(float v) {
    v += dppf<0xB1>(v);
    v += dppf<0x4E>(v);
    v += dppf<0x141>(v);
    v += dppf<0x140>(v);
    return v;
}
__device__ __forceinline__ float wave_sum(float v) {
    v = row16_sum(v);
    v += __shfl_xor(v, 16, 64);
    v += __shfl_xor(v, 32, 64);
    return v;
}

__device__ __forceinline__ int cell_coord(float v) {
    int c = (int)(v * 4.0f);
    return min(3, max(0, c));
}

// ws layout (floats): [0..767] W_eff (256x3 row-major), [768..1023] b_eff

// ---------------------------------------------------------------------------
// Merged prep, 2 output rows per block (128 blocks): halves W2 L2 traffic
// (prep is L2-BW-bound: R9 measured 2.9us/rep = 22 TB/s on 64 MB).
// W_eff = (W3*W2)*W1, b_eff = (W3*W2)*b1 + W3*b2 + b3 (weights-only reassoc).
// ---------------------------------------------------------------------------
__global__ __launch_bounds__(256) void prep_kernel(
    const float* __restrict__ w1, const float* __restrict__ b1,
    const float* __restrict__ w2, const float* __restrict__ b2,
    const float* __restrict__ w3, const float* __restrict__ b3,
    float* __restrict__ ws)
{
    __shared__ float  w3row[2][CCH];
    __shared__ float4 wpart[2][4];
    int o0 = blockIdx.x * 2, c = threadIdx.x;

    float w3c0 = w3[(o0 + 0) * CCH + c];           // coalesced
    float w3c1 = w3[(o0 + 1) * CCH + c];
    w3row[0][c] = w3c0;
    w3row[1][c] = w3c1;
    __syncthreads();

    float a0 = 0.f, a1 = 0.f, a2 = 0.f, a3 = 0.f;  // row 0 partials
    float b0 = 0.f, b1p = 0.f, b2p = 0.f, b3p = 0.f; // row 1 partials
    const float* w2c = w2 + c;
    for (int k = 0; k < CCH; k += 4) {
        float q0 = w2c[(k + 0) * CCH];
        float q1 = w2c[(k + 1) * CCH];
        float q2 = w2c[(k + 2) * CCH];
        float q3 = w2c[(k + 3) * CCH];
        a0 = fmaf(w3row[0][k + 0], q0, a0);
        a1 = fmaf(w3row[0][k + 1], q1, a1);
        a2 = fmaf(w3row[0][k + 2], q2, a2);
        a3 = fmaf(w3row[0][k + 3], q3, a3);
        b0  = fmaf(w3row[1][k + 0], q0, b0);
        b1p = fmaf(w3row[1][k + 1], q1, b1p);
        b2p = fmaf(w3row[1][k + 2], q2, b2p);
        b3p = fmaf(w3row[1][k + 3], q3, b3p);
    }
    float accA = (a0 + a1) + (a2 + a3);            // M[o0][c]
    float accB = (b0 + b1p) + (b2p + b3p);         // M[o0+1][c]

    float w1x = w1[c * 3 + 0], w1y = w1[c * 3 + 1], w1z = w1[c * 3 + 2];
    float b1c = b1[c], b2c = b2[c];

    float4 vA = make_float4(accA * w1x, accA * w1y, accA * w1z,
                            fmaf(accA, b1c, w3c0 * b2c));
    float4 vB = make_float4(accB * w1x, accB * w1y, accB * w1z,
                            fmaf(accB, b1c, w3c1 * b2c));
    vA.x = wave_sum(vA.x); vA.y = wave_sum(vA.y);
    vA.z = wave_sum(vA.z); vA.w = wave_sum(vA.w);
    vB.x = wave_sum(vB.x); vB.y = wave_sum(vB.y);
    vB.z = wave_sum(vB.z); vB.w = wave_sum(vB.w);
    if ((c & 63) == 0) {
        wpart[0][c >> 6] = vA;
        wpart[1][c >> 6] = vB;
    }
    __syncthreads();
    if (c < 2) {
        int o = o0 + c;
        float4 p0 = wpart[c][0], p1 = wpart[c][1], p2 = wpart[c][2], p3 = wpart[c][3];
        ws[o * 3 + 0] = (p0.x + p1.x) + (p2.x + p3.x);
        ws[o * 3 + 1] = (p0.y + p1.y) + (p2.y + p3.y);
        ws[o * 3 + 2] = (p0.z + p1.z) + (p2.z + p3.z);
        ws[3 * CCH + o] = (p0.w + p1.w) + (p2.w + p3.w) + b3[o];
    }
}

// ---------------------------------------------------------------------------
// pointsift: 1024 threads = 16 waves = 16 points/block.
// Phase A: fused in-block counting sort of the batch into 64 cells (4x4x4,
//   cell width 0.25 = radius): LDS hist -> wave-0 prefix scan -> atomic
//   scatter into scrd[] (coords + orig idx in .w). No global roundtrip.
// Phase B: per wave, pass-1 scans only the 9 contiguous z-runs of the
//   27-cell neighborhood (~500 candidates vs 2048; exact: |cell diff|>=2 in
//   any dim => d2 > r^2 in f32). Ballot compaction of valid candidates.
// Pass-2 + argmin use u64 lex keys (d2_bits<<32 | orig_idx): selection is
//   fully order-independent, so the atomic scatter order cannot leak into
//   the output, and d2-ties resolve to min original index (numpy first-min).
// ---------------------------------------------------------------------------
__global__ __launch_bounds__(1024) void pointsift_kernel(
    const float* __restrict__ x,   // [Bp, NPTS, 3]
    const float* __restrict__ ws,  // W_eff[256*3] then b_eff[256]
    float* __restrict__ out)       // [Bp, NPTS, 21]
{
    __shared__ float4 scrd[NPTS];                  // sorted (x,y,z,idx_bits) 32 KB
    __shared__ unsigned sstart[66];
    __shared__ unsigned shist[64];
    __shared__ unsigned scur[64];
    __shared__ unsigned short slist[16][CAP];      // 10 KB

    int tid = threadIdx.x;
    int batch = blockIdx.x >> 7;                   // 128 blocks per batch
    int n0    = (blockIdx.x & 127) * 16;
    const float* xb = x + (size_t)batch * NPTS * 3;

    // ---- phase A: stage 2 points/thread, histogram ----
    if (tid < 64) shist[tid] = 0;
    __syncthreads();

    // coalesced 24B/thread: points 2t, 2t+1
    float2 f0 = *(const float2*)(xb + 6 * tid + 0);
    float2 f1 = *(const float2*)(xb + 6 * tid + 2);
    float2 f2 = *(const float2*)(xb + 6 * tid + 4);
    float3 p0 = make_float3(f0.x, f0.y, f1.x);
    float3 p1 = make_float3(f1.y, f2.x, f2.y);
    int c0 = (cell_coord(p0.x) << 4) | (cell_coord(p0.y) << 2) | cell_coord(p0.z);
    int c1 = (cell_coord(p1.x) << 4) | (cell_coord(p1.y) << 2) | cell_coord(p1.z);
    atomicAdd(&shist[c0], 1u);
    atomicAdd(&shist[c1], 1u);
    __syncthreads();

    // wave 0: exclusive prefix scan of 64 cells
    if (tid < 64) {
        unsigned v = shist[tid];
        unsigned incl = v;
#pragma unroll
        for (int s = 1; s < 64; s <<= 1) {
            unsigned o = __shfl_up(incl, s, 64);
            if (tid >= s) incl += o;
        }
        unsigned excl = incl - v;
        sstart[tid] = excl;
        scur[tid] = excl;
        if (tid == 63) sstart[64] = NPTS;
    }
    __syncthreads();

    // scatter (order within cell nondeterministic -> selection is lex, safe)
    {
        unsigned q0 = atomicAdd(&scur[c0], 1u);
        scrd[q0] = make_float4(p0.x, p0.y, p0.z, __uint_as_float(2u * tid));
        unsigned q1 = atomicAdd(&scur[c1], 1u);
        scrd[q1] = make_float4(p1.x, p1.y, p1.z, __uint_as_float(2u * tid + 1u));
    }

    int wave = tid >> 6;
    int lane = tid & 63;
    int n = n0 + wave;

    float3 cpt = *(const float3*)(xb + 3 * n);
    float cx = cpt.x, cy = cpt.y, cz = cpt.z;

    __syncthreads();                               // sorted arrays ready

    int ccx = cell_coord(cx), ccy = cell_coord(cy), ccz = cell_coord(cz);
    int zlo = ccz > 0 ? ccz - 1 : 0;
    int zhi = ccz < 3 ? ccz + 1 : 3;

    unsigned short* slw = slist[wave];

    // ---- pass 1: validity + ballot compaction over 9 cell-runs ----
    unsigned cnt = 0;
    for (int di = -1; di <= 1; ++di) {
        int a = ccx + di;
        if ((unsigned)a > 3u) continue;
        for (int dj = -1; dj <= 1; ++dj) {
            int bc = ccy + dj;
            if ((unsigned)bc > 3u) continue;
            int base = (a << 4) | (bc << 2);
            unsigned s0 = sstart[base + zlo];
            unsigned e0 = sstart[base + zhi + 1];
            for (unsigned pp = s0; pp < e0; pp += 64) {
                unsigned pos = pp + lane;
                bool inb = pos < e0;
                float4 p = scrd[inb ? pos : 0];
                float dx = p.x - cx, dy = p.y - cy, dz = p.z - cz;
                // bit-match numpy: (dx*dx + dy*dy) + dz*dz, no FMA contraction
                float d2 = __fadd_rn(__fadd_rn(__fmul_rn(dx, dx), __fmul_rn(dy, dy)),
                                     __fmul_rn(dz, dz));
                bool valid = inb && (d2 > 1e-10f) && (d2 < 0.0625f);
                unsigned long long mask = __ballot(valid);
                if (valid && cnt <= CAPU) {
                    unsigned below = __builtin_amdgcn_mbcnt_hi(
                        (unsigned)(mask >> 32),
                        __builtin_amdgcn_mbcnt_lo((unsigned)mask, 0u));
                    slw[cnt + below] = (unsigned short)pos;
                }
                cnt += (unsigned)__popcll(mask);
            }
        }
    }

    // ---- pass 2: per-octant lex-min via u64 key (d2_bits<<32 | orig idx) ----
    unsigned long long bk[8];
#pragma unroll
    for (int i = 0; i < 8; ++i)
        bk[i] = (0x7f800000ULL << 32) | (unsigned)n;   // (inf, self)

    if (cnt <= CAPU) {
        int cn = (int)cnt;
        for (int t = lane; t < cn; t += 64) {
            int pos = slw[t];
            float4 p = scrd[pos];
            unsigned m = __float_as_uint(p.w);         // original index
            float dx = p.x - cx, dy = p.y - cy, dz = p.z - cz;
            float d2 = __fadd_rn(__fadd_rn(__fmul_rn(dx, dx), __fmul_rn(dy, dy)),
                                 __fmul_rn(dz, dz));
            // exact octant per reference: trunc(d+1.0) in {0,1}
            int oct = 4 * (int)(dx + 1.0f) + 2 * (int)(dy + 1.0f) + (int)(dz + 1.0f);
            unsigned long long key =
                ((unsigned long long)__float_as_uint(d2) << 32) | m;
#pragma unroll
            for (int i = 0; i < 8; ++i) {
                bool upd = (oct == i) && (key < bk[i]);
                bk[i] = upd ? key : bk[i];
            }
        }
    } else {
        // 11-sigma-rare; exact fallback: scan the whole sorted array
        for (int pos = lane; pos < NPTS; pos += 64) {
            float4 p = scrd[pos];
            unsigned m = __float_as_uint(p.w);
            float dx = p.x - cx, dy = p.y - cy, dz = p.z - cz;
            float d2 = __fadd_rn(__fadd_rn(__fmul_rn(dx, dx), __fmul_rn(dy, dy)),
                                 __fmul_rn(dz, dz));
            bool valid = (d2 > 1e-10f) && (d2 < 0.0625f);
            int oct = 4 * (int)(dx + 1.0f) + 2 * (int)(dy + 1.0f) + (int)(dz + 1.0f);
            unsigned long long key =
                ((unsigned long long)__float_as_uint(d2) << 32) | m;
#pragma unroll
            for (int i = 0; i < 8; ++i) {
                bool upd = valid && (oct == i) && (key < bk[i]);
                bk[i] = upd ? key : bk[i];
            }
        }
    }

    // ---- cross-lane argmin: DPP f32 min on d2; ties -> integer min of idx ----
    int nidx[8];
#pragma unroll
    for (int i = 0; i < 8; ++i) {
        float bdf = __uint_as_float((unsigned)(bk[i] >> 32));
        int   bii = (int)(unsigned)bk[i];
        float mv = row16_min(bdf);
        mv = fminf(mv, __shfl_xor(mv, 16, 64));
        mv = fminf(mv, __shfl_xor(mv, 32, 64));
        unsigned long long mk = __ballot(bdf == mv);   // wave-uniform
        if (__popcll(mk) == 1) {
            nidx[i] = __builtin_amdgcn_readlane(bii, (int)__builtin_ctzll(mk));
        } else {
            // ties (or empty octant: mv=inf, all lanes match, idx=n everywhere)
            int mm = (bdf == mv) ? bii : 0x7FFFFFFF;
#pragma unroll
            for (int s = 32; s > 0; s >>= 1) {
                int o = __shfl_xor(mm, s, 64);
                mm = o < mm ? o : mm;
            }
            nidx[i] = mm;
        }
    }

    // ---- fused affine + SPP: lane handles channels 4*lane..4*lane+3 ----
    const float4* wsv = (const float4*)ws;
    float4 wa = wsv[lane * 3 + 0];
    float4 wb = wsv[lane * 3 + 1];
    float4 wc = wsv[lane * 3 + 2];
    float4 be = ((const float4*)(ws + 3 * CCH))[lane];
    float w[4][3] = {{wa.x, wa.y, wa.z}, {wa.w, wb.x, wb.y},
                     {wb.z, wb.w, wc.x}, {wc.y, wc.z, wc.w}};
    float bev[4] = {be.x, be.y, be.z, be.w};

    float m16[4];
#pragma unroll
    for (int i = 0; i < 4; ++i) m16[i] = -__builtin_inff();
#pragma unroll
    for (int k = 0; k < 8; ++k) {
        float3 p = *(const float3*)(xb + 3 * nidx[k]);  // wave-uniform L1 read
        float gx = p.x - cx, gy = p.y - cy, gz = p.z - cz;
#pragma unroll
        for (int q = 0; q < 4; ++q) {
            float h = fmaf(gx, w[q][0], fmaf(gy, w[q][1], fmaf(gz, w[q][2], bev[q])));
            m16[k >> 1] = fmaxf(m16[k >> 1], h);
        }
    }

    float t[4], u[4];
#pragma unroll
    for (int i = 0; i < 4; ++i) {
        m16[i] = row16_max(m16[i]);
        t[i] = fmaxf(m16[i], __shfl_xor(m16[i], 16, 64));
        u[i] = fmaxf(t[i], __shfl_xor(t[i], 32, 64));
    }

    float* op = out + ((size_t)batch * NPTS + n) * 21;
    if ((lane & 15) == 0) {
        int j = lane >> 4;
#pragma unroll
        for (int i = 0; i < 4; ++i)
            op[i * 4 + j] = m16[i];
    }
    if (lane == 0 || lane == 32) {
        int j2 = lane >> 5;
        op[16 + 0 * 2 + j2] = fmaxf(t[0], t[1]);
        op[16 + 1 * 2 + j2] = fmaxf(t[2], t[3]);
    }
    if (lane == 0) {
        op[20] = fmaxf(fmaxf(u[0], u[1]), fmaxf(u[2], u[3]));
    }
}

extern "C" void kernel_launch(void* const* d_in, const int* in_sizes, int n_in,
                              void* d_out, int out_size, void* d_ws, size_t ws_size,
                              hipStream_t stream) {
    const float* x  = (const float*)d_in[0];
    const float* w1 = (const float*)d_in[1];
    const float* b1 = (const float*)d_in[2];
    const float* w2 = (const float*)d_in[3];
    const float* b2 = (const float*)d_in[4];
    const float* w3 = (const float*)d_in[5];
    const float* b3 = (const float*)d_in[6];
    float* out = (float*)d_out;
    float* ws  = (float*)d_ws;

    prep_kernel<<<CCH / 2, CCH, 0, stream>>>(w1, b1, w2, b2, w3, b3, ws);

    int Bp = in_sizes[0] / (NPTS * 3);             // B*T = 4
    pointsift_kernel<<<Bp * (NPTS / 16), 1024, 0, stream>>>(x, ws, out);
}

// Round 11
// 22.201 us; speedup vs baseline: 6.1747x; 1.1858x over previous
//
#include <hip/hip_runtime.h>

#define NPTS 2048
#define CCH  256

// ---- DPP cross-lane helpers (VALU pipe, no LDS) ----
template <int CTRL>
__device__ __forceinline__ float dppf(float v) {
    return __int_as_float(__builtin_amdgcn_update_dpp(
        0, __float_as_int(v), CTRL, 0xF, 0xF, true));
}
__device__ __forceinline__ float row16_max(float v) {
    v = fmaxf(v, dppf<0xB1>(v));
    v = fmaxf(v, dppf<0x4E>(v));
    v = fmaxf(v, dppf<0x141>(v));
    v = fmaxf(v, dppf<0x140>(v));
    return v;
}
__device__ __forceinline__ float row16_sum(float v) {
    v += dppf<0xB1>(v);
    v += dppf<0x4E>(v);
    v += dppf<0x141>(v);
    v += dppf<0x140>(v);
    return v;
}
__device__ __forceinline__ float wave_sum(float v) {
    v = row16_sum(v);
    v += __shfl_xor(v, 16, 64);
    v += __shfl_xor(v, 32, 64);
    return v;
}

__device__ __forceinline__ int cell_coord(float v) {
    int c = (int)(v * 4.0f);
    return min(3, max(0, c));
}

// ws layout (floats): [0..767] W_eff (256x3 row-major), [768..1023] b_eff

// ---------------------------------------------------------------------------
// Merged prep, 2 output rows per block (128 blocks): W2 L2 traffic halved.
// W_eff = (W3*W2)*W1, b_eff = (W3*W2)*b1 + W3*b2 + b3 (weights-only reassoc).
// ---------------------------------------------------------------------------
__global__ __launch_bounds__(256) void prep_kernel(
    const float* __restrict__ w1, const float* __restrict__ b1,
    const float* __restrict__ w2, const float* __restrict__ b2,
    const float* __restrict__ w3, const float* __restrict__ b3,
    float* __restrict__ ws)
{
    __shared__ float  w3row[2][CCH];
    __shared__ float4 wpart[2][4];
    int o0 = blockIdx.x * 2, c = threadIdx.x;

    float w3c0 = w3[(o0 + 0) * CCH + c];           // coalesced
    float w3c1 = w3[(o0 + 1) * CCH + c];
    w3row[0][c] = w3c0;
    w3row[1][c] = w3c1;
    __syncthreads();

    float a0 = 0.f, a1 = 0.f, a2 = 0.f, a3 = 0.f;    // row 0 partials
    float b0 = 0.f, b1p = 0.f, b2p = 0.f, b3p = 0.f; // row 1 partials
    const float* w2c = w2 + c;
    for (int k = 0; k < CCH; k += 4) {
        float q0 = w2c[(k + 0) * CCH];
        float q1 = w2c[(k + 1) * CCH];
        float q2 = w2c[(k + 2) * CCH];
        float q3 = w2c[(k + 3) * CCH];
        a0 = fmaf(w3row[0][k + 0], q0, a0);
        a1 = fmaf(w3row[0][k + 1], q1, a1);
        a2 = fmaf(w3row[0][k + 2], q2, a2);
        a3 = fmaf(w3row[0][k + 3], q3, a3);
        b0  = fmaf(w3row[1][k + 0], q0, b0);
        b1p = fmaf(w3row[1][k + 1], q1, b1p);
        b2p = fmaf(w3row[1][k + 2], q2, b2p);
        b3p = fmaf(w3row[1][k + 3], q3, b3p);
    }
    float accA = (a0 + a1) + (a2 + a3);            // M[o0][c]
    float accB = (b0 + b1p) + (b2p + b3p);         // M[o0+1][c]

    float w1x = w1[c * 3 + 0], w1y = w1[c * 3 + 1], w1z = w1[c * 3 + 2];
    float b1c = b1[c], b2c = b2[c];

    float4 vA = make_float4(accA * w1x, accA * w1y, accA * w1z,
                            fmaf(accA, b1c, w3c0 * b2c));
    float4 vB = make_float4(accB * w1x, accB * w1y, accB * w1z,
                            fmaf(accB, b1c, w3c1 * b2c));
    vA.x = wave_sum(vA.x); vA.y = wave_sum(vA.y);
    vA.z = wave_sum(vA.z); vA.w = wave_sum(vA.w);
    vB.x = wave_sum(vB.x); vB.y = wave_sum(vB.y);
    vB.z = wave_sum(vB.z); vB.w = wave_sum(vB.w);
    if ((c & 63) == 0) {
        wpart[0][c >> 6] = vA;
        wpart[1][c >> 6] = vB;
    }
    __syncthreads();
    if (c < 2) {
        int o = o0 + c;
        float4 p0 = wpart[c][0], p1 = wpart[c][1], p2 = wpart[c][2], p3 = wpart[c][3];
        ws[o * 3 + 0] = (p0.x + p1.x) + (p2.x + p3.x);
        ws[o * 3 + 1] = (p0.y + p1.y) + (p2.y + p3.y);
        ws[o * 3 + 2] = (p0.z + p1.z) + (p2.z + p3.z);
        ws[3 * CCH + o] = (p0.w + p1.w) + (p2.w + p3.w) + b3[o];
    }
}

// ---------------------------------------------------------------------------
// pointsift: 1024 threads = 16 waves = 16 points/block.
// Phase A: in-block counting sort into 64 cells (4x4x4, cell width = radius).
// Phase B: single fused pass over the 9 contiguous cell-runs of the 27-cell
//   neighborhood (~500 candidates). Each VALID candidate issues ONE
//   ds_min_u64 on its octant's per-wave slot, key = (d2_bits<<32)|orig_idx.
//   Min is associative/commutative -> scatter order can't leak; d2-ties
//   resolve to min original index = numpy argmin first-min; valid => |d|<0.25
//   => oct in [0,7]. Empty octant keeps init (inf, self) -> grouped = 0.
//   No compaction list, no CAP fallback, no cross-lane argmin butterflies.
// ---------------------------------------------------------------------------
__global__ __launch_bounds__(1024) void pointsift_kernel(
    const float* __restrict__ x,   // [Bp, NPTS, 3]
    const float* __restrict__ ws,  // W_eff[256*3] then b_eff[256]
    float* __restrict__ out)       // [Bp, NPTS, 21]
{
    __shared__ float4 scrd[NPTS];                  // sorted (x,y,z,idx_bits) 32 KB
    __shared__ unsigned sstart[66];
    __shared__ unsigned shist[64];
    __shared__ unsigned scur[64];
    __shared__ unsigned long long soct[16][8];     // per-wave octant min slots 1 KB

    int tid = threadIdx.x;
    int batch = blockIdx.x >> 7;                   // 128 blocks per batch
    int n0    = (blockIdx.x & 127) * 16;
    const float* xb = x + (size_t)batch * NPTS * 3;

    // ---- phase A: histogram (2 points/thread, coalesced 24B) ----
    if (tid < 64) shist[tid] = 0;
    __syncthreads();

    float2 f0 = *(const float2*)(xb + 6 * tid + 0);
    float2 f1 = *(const float2*)(xb + 6 * tid + 2);
    float2 f2 = *(const float2*)(xb + 6 * tid + 4);
    float3 p0 = make_float3(f0.x, f0.y, f1.x);
    float3 p1 = make_float3(f1.y, f2.x, f2.y);
    int c0 = (cell_coord(p0.x) << 4) | (cell_coord(p0.y) << 2) | cell_coord(p0.z);
    int c1 = (cell_coord(p1.x) << 4) | (cell_coord(p1.y) << 2) | cell_coord(p1.z);
    atomicAdd(&shist[c0], 1u);
    atomicAdd(&shist[c1], 1u);
    __syncthreads();

    // wave 0: exclusive prefix scan of 64 cells
    if (tid < 64) {
        unsigned v = shist[tid];
        unsigned incl = v;
#pragma unroll
        for (int s = 1; s < 64; s <<= 1) {
            unsigned o = __shfl_up(incl, s, 64);
            if (tid >= s) incl += o;
        }
        unsigned excl = incl - v;
        sstart[tid] = excl;
        scur[tid] = excl;
        if (tid == 63) sstart[64] = NPTS;
    }
    __syncthreads();

    // scatter (within-cell order nondeterministic -> selection is lex-min, safe)
    {
        unsigned q0 = atomicAdd(&scur[c0], 1u);
        scrd[q0] = make_float4(p0.x, p0.y, p0.z, __uint_as_float(2u * tid));
        unsigned q1 = atomicAdd(&scur[c1], 1u);
        scrd[q1] = make_float4(p1.x, p1.y, p1.z, __uint_as_float(2u * tid + 1u));
    }

    int wave = tid >> 6;
    int lane = tid & 63;
    int n = n0 + wave;

    float3 cpt = *(const float3*)(xb + 3 * n);
    float cx = cpt.x, cy = cpt.y, cz = cpt.z;

    // init this wave's 8 octant slots: (inf, self). Same-wave DS ordering
    // guarantees init -> atomics -> readback without a barrier.
    if (lane < 8)
        soct[wave][lane] = (0x7f800000ULL << 32) | (unsigned)n;

    __syncthreads();                               // sorted arrays ready

    int ccx = cell_coord(cx), ccy = cell_coord(cy), ccz = cell_coord(cz);
    int zlo = ccz > 0 ? ccz - 1 : 0;
    int zhi = ccz < 3 ? ccz + 1 : 3;

    // ---- phase B: fused scan + octant lex-min via ds_min_u64 ----
    for (int di = -1; di <= 1; ++di) {
        int a = ccx + di;
        if ((unsigned)a > 3u) continue;
        for (int dj = -1; dj <= 1; ++dj) {
            int bc = ccy + dj;
            if ((unsigned)bc > 3u) continue;
            int base = (a << 4) | (bc << 2);
            unsigned s0 = sstart[base + zlo];
            unsigned e0 = sstart[base + zhi + 1];
            for (unsigned pp = s0 + lane; pp < e0; pp += 64) {
                float4 p = scrd[pp];
                float dx = p.x - cx, dy = p.y - cy, dz = p.z - cz;
                // bit-match numpy: (dx*dx + dy*dy) + dz*dz, no FMA contraction
                float d2 = __fadd_rn(__fadd_rn(__fmul_rn(dx, dx), __fmul_rn(dy, dy)),
                                     __fmul_rn(dz, dz));
                if ((d2 > 1e-10f) && (d2 < 0.0625f)) {
                    // exact octant per reference: trunc(d+1.0) in {0,1}
                    int oct = 4 * (int)(dx + 1.0f) + 2 * (int)(dy + 1.0f) + (int)(dz + 1.0f);
                    unsigned long long key =
                        ((unsigned long long)__float_as_uint(d2) << 32) |
                        __float_as_uint(p.w);
                    __hip_atomic_fetch_min(&soct[wave][oct], key,
                                           __ATOMIC_RELAXED,
                                           __HIP_MEMORY_SCOPE_WORKGROUP);
                }
            }
        }
    }

    // ---- readback: low 32 bits of each slot = selected original index ----
    int nidx[8];
#pragma unroll
    for (int k = 0; k < 8; ++k)
        nidx[k] = (int)(unsigned)soct[wave][k];    // broadcast LDS reads

    // ---- fused affine + SPP: lane handles channels 4*lane..4*lane+3 ----
    const float4* wsv = (const float4*)ws;
    float4 wa = wsv[lane * 3 + 0];
    float4 wb = wsv[lane * 3 + 1];
    float4 wc = wsv[lane * 3 + 2];
    float4 be = ((const float4*)(ws + 3 * CCH))[lane];
    float w[4][3] = {{wa.x, wa.y, wa.z}, {wa.w, wb.x, wb.y},
                     {wb.z, wb.w, wc.x}, {wc.y, wc.z, wc.w}};
    float bev[4] = {be.x, be.y, be.z, be.w};

    float m16[4];
#pragma unroll
    for (int i = 0; i < 4; ++i) m16[i] = -__builtin_inff();
#pragma unroll
    for (int k = 0; k < 8; ++k) {
        float3 p = *(const float3*)(xb + 3 * nidx[k]);  // wave-uniform L1 read
        float gx = p.x - cx, gy = p.y - cy, gz = p.z - cz;
#pragma unroll
        for (int q = 0; q < 4; ++q) {
            float h = fmaf(gx, w[q][0], fmaf(gy, w[q][1], fmaf(gz, w[q][2], bev[q])));
            m16[k >> 1] = fmaxf(m16[k >> 1], h);
        }
    }

    float t[4], u[4];
#pragma unroll
    for (int i = 0; i < 4; ++i) {
        m16[i] = row16_max(m16[i]);
        t[i] = fmaxf(m16[i], __shfl_xor(m16[i], 16, 64));
        u[i] = fmaxf(t[i], __shfl_xor(t[i], 32, 64));
    }

    float* op = out + ((size_t)batch * NPTS + n) * 21;
    if ((lane & 15) == 0) {
        int j = lane >> 4;
#pragma unroll
        for (int i = 0; i < 4; ++i)
            op[i * 4 + j] = m16[i];
    }
    if (lane == 0 || lane == 32) {
        int j2 = lane >> 5;
        op[16 + 0 * 2 + j2] = fmaxf(t[0], t[1]);
        op[16 + 1 * 2 + j2] = fmaxf(t[2], t[3]);
    }
    if (lane == 0) {
        op[20] = fmaxf(fmaxf(u[0], u[1]), fmaxf(u[2], u[3]));
    }
}

extern "C" void kernel_launch(void* const* d_in, const int* in_sizes, int n_in,
                              void* d_out, int out_size, void* d_ws, size_t ws_size,
                              hipStream_t stream) {
    const float* x  = (const float*)d_in[0];
    const float* w1 = (const float*)d_in[1];
    const float* b1 = (const float*)d_in[2];
    const float* w2 = (const float*)d_in[3];
    const float* b2 = (const float*)d_in[4];
    const float* w3 = (const float*)d_in[5];
    const float* b3 = (const float*)d_in[6];
    float* out = (float*)d_out;
    float* ws  = (float*)d_ws;

    prep_kernel<<<CCH / 2, CCH, 0, stream>>>(w1, b1, w2, b2, w3, b3, ws);

    int Bp = in_sizes[0] / (NPTS * 3);             // B*T = 4
    pointsift_kernel<<<Bp * (NPTS / 16), 1024, 0, stream>>>(x, ws, out);
}